// Round 8
// baseline (301.961 us; speedup 1.0000x reference)
//
#include <hip/hip_runtime.h>
#include <math.h>

#define WIDTH   512
#define NPLANE  48          // 16 batch * 3 channels
#define TW      32          // tile width  (output cols)
#define TH      64          // tile height (output rows)
#define SROWS   74          // h-blurred rows needed = TH + 10
#define HBS     76          // hb slots/col: >=74, %32==12 (bank spread), *4B 16B-aligned
#define GX      16
#define GY      8
#define NBLOCKS (GX*GY*NPLANE)   // 6144
#define NPIX    (16.0*3.0*512.0*512.0)

struct GaussW { float w[11]; };

// 8 outputs from a 18-word window (vin = window+0 corresponds to tap j+k)
__device__ __forceinline__ void blur8(const float* vin, const GaussW& gw, float* o)
{
    #pragma unroll
    for (int t = 0; t < 8; ++t) {
        float s = vin[t] * gw.w[0];
        #pragma unroll
        for (int k = 1; k < 11; ++k) s = fmaf(gw.w[k], vin[t + k], s);
        o[t] = s;
    }
}

__global__ __launch_bounds__(512, 6)
void ssim_tile_kernel(const float* __restrict__ img1,
                      const float* __restrict__ img2,
                      float* __restrict__ partial, GaussW gw)
{
    // transposed h-blur buffer: [q][col][row], col stride HBS words
    __shared__ __align__(16) float hb[5 * TW * HBS];   // 48640 B -> 3 blocks/CU
    __shared__ float red[8];

    const int tid = threadIdx.x;
    const int bx = blockIdx.x, by = blockIdx.y, bz = blockIdx.z;
    const float* __restrict__ p1 = img1 + (size_t)bz * (WIDTH * WIDTH);
    const float* __restrict__ p2 = img2 + (size_t)bz * (WIDTH * WIDTH);
    const int gx0 = bx * TW - 8;    // first window col (16B-aligned loads)
    const int gy0 = by * TH - 5;    // first h-row
    const bool interior = ((unsigned)(bx - 1) < 14u) & ((unsigned)(by - 1) < 6u);

    // ---- h-pass: 888 items = 3 classes x 74 rows x 4 colgroups(8-wide) ----
    // item = g*296 + r*4 + cgi  (cgi fastest -> 4 lanes share a row: coalesced)
    // g0: img1 -> q0,q2 ; g1: img2 -> q1,q3 ; g2: img1*img2 -> q4
    #pragma unroll
    for (int round = 0; round < 2; ++round) {
        int it = tid + (round << 9);
        if (it < 888) {
            int g   = it / 296;
            int rem = it - g * 296;
            int r   = rem >> 2;
            int c0  = (rem & 3) << 3;
            int grow  = gy0 + r;
            int gcol0 = gx0 + c0;
            float ld[24];
            if (g < 2) {
                const float* __restrict__ bp = (g ? p2 : p1);
                if (interior) {
                    const float* wp = bp + grow * WIDTH + gcol0;
                    #pragma unroll
                    for (int p = 0; p < 6; ++p) {
                        float4 v = *(const float4*)(wp + (p << 2));
                        ld[4*p] = v.x; ld[4*p+1] = v.y; ld[4*p+2] = v.z; ld[4*p+3] = v.w;
                    }
                } else {
                    bool rok = (unsigned)grow < WIDTH;
                    #pragma unroll
                    for (int w = 0; w < 24; ++w) {
                        int gc = gcol0 + w;
                        ld[w] = (rok && (unsigned)gc < WIDTH) ? bp[grow * WIDTH + gc] : 0.f;
                    }
                }
                float oa[8], ob[8];
                blur8(ld + 3, gw, oa);
                #pragma unroll
                for (int i = 3; i < 21; ++i) ld[i] *= ld[i];
                blur8(ld + 3, gw, ob);
                const int qa = g * TW + c0, qb = (g + 2) * TW + c0;
                #pragma unroll
                for (int j = 0; j < 8; ++j) hb[(qa + j) * HBS + r] = oa[j];
                #pragma unroll
                for (int j = 0; j < 8; ++j) hb[(qb + j) * HBS + r] = ob[j];
            } else {
                float lb[24];
                if (interior) {
                    const float* wa = p1 + grow * WIDTH + gcol0;
                    const float* wb = p2 + grow * WIDTH + gcol0;
                    #pragma unroll
                    for (int p = 0; p < 6; ++p) {
                        float4 v = *(const float4*)(wa + (p << 2));
                        ld[4*p] = v.x; ld[4*p+1] = v.y; ld[4*p+2] = v.z; ld[4*p+3] = v.w;
                        float4 u = *(const float4*)(wb + (p << 2));
                        lb[4*p] = u.x; lb[4*p+1] = u.y; lb[4*p+2] = u.z; lb[4*p+3] = u.w;
                    }
                } else {
                    bool rok = (unsigned)grow < WIDTH;
                    #pragma unroll
                    for (int w = 0; w < 24; ++w) {
                        int gc = gcol0 + w;
                        bool ok = rok && (unsigned)gc < WIDTH;
                        int idx = grow * WIDTH + gc;
                        ld[w] = ok ? p1[idx] : 0.f;
                        lb[w] = ok ? p2[idx] : 0.f;
                    }
                }
                #pragma unroll
                for (int i = 3; i < 21; ++i) ld[i] *= lb[i];
                float oa[8];
                blur8(ld + 3, gw, oa);
                const int qa = 4 * TW + c0;
                #pragma unroll
                for (int j = 0; j < 8; ++j) hb[(qa + j) * HBS + r] = oa[j];
            }
        }
    }
    __syncthreads();   // the ONLY data barrier

    // ---- v-pass: thread = (col c, rows r0..r0+3); 32 x 16 = 512 items ----
    const int c  = tid & 31;
    const int r0 = (tid >> 5) << 2;
    float acc[5][4];
    #pragma unroll
    for (int q = 0; q < 5; ++q) {
        const int base = (q * TW + c) * HBS + r0;
        float win[16];
        #pragma unroll
        for (int k = 0; k < 4; ++k) {
            float4 v = *(const float4*)&hb[base + (k << 2)];
            win[4*k] = v.x; win[4*k+1] = v.y; win[4*k+2] = v.z; win[4*k+3] = v.w;
        }
        #pragma unroll
        for (int i = 0; i < 4; ++i) {
            float s = win[i] * gw.w[0];
            #pragma unroll
            for (int k = 1; k < 11; ++k) s = fmaf(gw.w[k], win[i + k], s);
            acc[q][i] = s;
        }
    }

    // ---- SSIM map (fast rcp + 1 NR) + block reduction ----
    const float C1 = 0.01f * 0.01f, C2 = 0.03f * 0.03f;
    float ssum = 0.f;
    #pragma unroll
    for (int i = 0; i < 4; ++i) {
        float a = acc[0][i], b = acc[1][i];
        float ab = a * b, a2 = a * a, b2 = b * b;
        float s11 = acc[2][i] - a2;
        float s22 = acc[3][i] - b2;
        float s12 = acc[4][i] - ab;
        float num = (2.f * ab + C1) * (2.f * s12 + C2);
        float den = (a2 + b2 + C1) * (s11 + s22 + C2);
        float inv = __builtin_amdgcn_rcpf(den);
        inv = inv * fmaf(-den, inv, 2.0f);          // 1 Newton step
        ssum = fmaf(num, inv, ssum);
    }

    #pragma unroll
    for (int off = 32; off > 0; off >>= 1) ssum += __shfl_down(ssum, off);
    if ((tid & 63) == 0) red[tid >> 6] = ssum;
    __syncthreads();
    if (tid == 0) {
        float t = 0.f;
        #pragma unroll
        for (int w = 0; w < 8; ++w) t += red[w];
        partial[bx + GX * (by + GY * bz)] = t;
    }
}

__global__ __launch_bounds__(1024)
void ssim_reduce_kernel(const float* __restrict__ partial, float* __restrict__ out)
{
    __shared__ double red[16];
    double s = 0.0;
    for (int i = threadIdx.x; i < NBLOCKS; i += 1024) s += (double)partial[i];
    #pragma unroll
    for (int off = 32; off > 0; off >>= 1) s += __shfl_down(s, off);
    if ((threadIdx.x & 63) == 0) red[threadIdx.x >> 6] = s;
    __syncthreads();
    if (threadIdx.x == 0) {
        double t = 0.0;
        #pragma unroll
        for (int w = 0; w < 16; ++w) t += red[w];
        out[0] = (float)(t / NPIX);
    }
}

extern "C" void kernel_launch(void* const* d_in, const int* in_sizes, int n_in,
                              void* d_out, int out_size, void* d_ws, size_t ws_size,
                              hipStream_t stream)
{
    GaussW gw;
    double g[11], sum = 0.0;
    for (int i = 0; i < 11; ++i) {
        double x = (double)(i - 5);
        g[i] = exp(-(x * x) / 4.5);
        sum += g[i];
    }
    for (int i = 0; i < 11; ++i) gw.w[i] = (float)(g[i] / sum);

    const float* img1 = (const float*)d_in[0];
    const float* img2 = (const float*)d_in[1];
    float* partial = (float*)d_ws;   // NBLOCKS floats; every slot written each launch
    float* out = (float*)d_out;

    dim3 grid(GX, GY, NPLANE);
    hipLaunchKernelGGL(ssim_tile_kernel, grid, dim3(512), 0, stream,
                       img1, img2, partial, gw);
    hipLaunchKernelGGL(ssim_reduce_kernel, dim3(1), dim3(1024), 0, stream,
                       partial, out);
}

// Round 10
// 212.025 us; speedup vs baseline: 1.4242x; 1.4242x over previous
//
#include <hip/hip_runtime.h>
#include <math.h>

#define WIDTH   512
#define NPLANE  48          // 16 batch * 3 channels
#define TW      32          // tile width  (output cols)
#define TH      64          // tile height (output rows)
#define SROWS   74          // h-blur rows needed = TH + 10
#define HBS     76          // hb slots/col: >=76 (reads to slot 75), 76%32==12 bank-spread
#define GX      16
#define GY      8
#define NBLOCKS (GX*GY*NPLANE)   // 6144
#define NPIX    (16.0*3.0*512.0*512.0)

struct GaussW { float w[11]; };

// 8 outputs from an 18-word window
__device__ __forceinline__ void blur8(const float* vin, const GaussW& gw, float* o)
{
    #pragma unroll
    for (int t = 0; t < 8; ++t) {
        float s = vin[t] * gw.w[0];
        #pragma unroll
        for (int k = 1; k < 11; ++k) s = fmaf(gw.w[k], vin[t + k], s);
        o[t] = s;
    }
}

__global__ __launch_bounds__(256, 3)
void ssim_tile_kernel(const float* __restrict__ img1,
                      const float* __restrict__ img2,
                      float* __restrict__ partial, GaussW gw)
{
    // transposed h-blur buffer: [q][col][row], col stride HBS words. 48640 B.
    __shared__ __align__(16) float hb[5 * TW * HBS];
    __shared__ float red[4];

    const int tid = threadIdx.x;
    const int bx = blockIdx.x, by = blockIdx.y, bz = blockIdx.z;
    const float* __restrict__ p1 = img1 + (size_t)bz * (WIDTH * WIDTH);
    const float* __restrict__ p2 = img2 + (size_t)bz * (WIDTH * WIDTH);
    const int gy0 = by * TH - 5;        // first h-row
    const int gxb = bx * TW - 8;        // load base col (16B-aligned)
    const bool colsafe = ((unsigned)(bx - 1) < 14u);

    // ---- h-pass: item = cg*74 + r (r fastest -> 2-way LDS writes, bulk loads)
    // each item: ONE (a,b) window pair -> ALL 5 quantities, 8 output cols
    #pragma unroll
    for (int round = 0; round < 2; ++round) {
        int it = tid + (round << 8);
        if (it < 4 * SROWS) {
            int cg = it / SROWS;
            int r  = it - cg * SROWS;
            int c0 = cg << 3;
            int grow = gy0 + r;
            int gc0  = gxb + (cg << 3);
            float a[24], b[24];
            bool rok = (unsigned)grow < WIDTH;
            if (colsafe & rok) {
                const float* wa = p1 + grow * WIDTH + gc0;
                const float* wb = p2 + grow * WIDTH + gc0;
                #pragma unroll
                for (int p = 0; p < 6; ++p) {           // 12 loads, one burst
                    float4 v = *(const float4*)(wa + (p << 2));
                    a[4*p]=v.x; a[4*p+1]=v.y; a[4*p+2]=v.z; a[4*p+3]=v.w;
                    float4 u = *(const float4*)(wb + (p << 2));
                    b[4*p]=u.x; b[4*p+1]=u.y; b[4*p+2]=u.z; b[4*p+3]=u.w;
                }
            } else if (!rok) {
                #pragma unroll
                for (int i = 0; i < 24; ++i) { a[i] = 0.f; b[i] = 0.f; }
            } else {
                #pragma unroll
                for (int i = 0; i < 24; ++i) {
                    int gc = gc0 + i;
                    bool ok = (unsigned)gc < WIDTH;
                    int idx = grow * WIDTH + gc;
                    a[i] = ok ? p1[idx] : 0.f;
                    b[i] = ok ? p2[idx] : 0.f;
                }
            }
            float o[8], t[18];
            blur8(a + 3, gw, o);                                   // q0: mu1h
            #pragma unroll
            for (int j = 0; j < 8; ++j) hb[(c0 + j) * HBS + r] = o[j];
            blur8(b + 3, gw, o);                                   // q1: mu2h
            #pragma unroll
            for (int j = 0; j < 8; ++j) hb[(TW + c0 + j) * HBS + r] = o[j];
            #pragma unroll
            for (int i = 0; i < 18; ++i) t[i] = a[3+i] * a[3+i];
            blur8(t, gw, o);                                       // q2: E[x^2]h
            #pragma unroll
            for (int j = 0; j < 8; ++j) hb[(2*TW + c0 + j) * HBS + r] = o[j];
            #pragma unroll
            for (int i = 0; i < 18; ++i) t[i] = b[3+i] * b[3+i];
            blur8(t, gw, o);                                       // q3: E[y^2]h
            #pragma unroll
            for (int j = 0; j < 8; ++j) hb[(3*TW + c0 + j) * HBS + r] = o[j];
            #pragma unroll
            for (int i = 0; i < 18; ++i) t[i] = a[3+i] * b[3+i];
            blur8(t, gw, o);                                       // q4: E[xy]h
            #pragma unroll
            for (int j = 0; j < 8; ++j) hb[(4*TW + c0 + j) * HBS + r] = o[j];
        }
    }
    __syncthreads();   // the only data barrier

    // ---- v-pass: thread = (col c, rows r0..r0+7); 32 x 8 = 256 items ----
    const int c  = tid & 31;
    const int r0 = (tid >> 5) << 3;
    float acc[5][8];
    #pragma unroll
    for (int q = 0; q < 5; ++q) {
        const int base = (q * TW + c) * HBS + r0;
        float win[20];
        #pragma unroll
        for (int k = 0; k < 5; ++k) {
            float4 v = *(const float4*)&hb[base + (k << 2)];
            win[4*k]=v.x; win[4*k+1]=v.y; win[4*k+2]=v.z; win[4*k+3]=v.w;
        }
        #pragma unroll
        for (int i = 0; i < 8; ++i) {
            float s = win[i] * gw.w[0];
            #pragma unroll
            for (int k = 1; k < 11; ++k) s = fmaf(gw.w[k], win[i + k], s);
            acc[q][i] = s;
        }
    }

    // ---- SSIM map (fast rcp + 1 NR) + block reduction ----
    const float C1 = 0.01f * 0.01f, C2 = 0.03f * 0.03f;
    float ssum = 0.f;
    #pragma unroll
    for (int i = 0; i < 8; ++i) {
        float a = acc[0][i], b = acc[1][i];
        float ab = a * b, a2 = a * a, b2 = b * b;
        float s11 = acc[2][i] - a2;
        float s22 = acc[3][i] - b2;
        float s12 = acc[4][i] - ab;
        float num = (2.f * ab + C1) * (2.f * s12 + C2);
        float den = (a2 + b2 + C1) * (s11 + s22 + C2);
        float inv = __builtin_amdgcn_rcpf(den);
        inv = inv * fmaf(-den, inv, 2.0f);          // 1 Newton step
        ssum = fmaf(num, inv, ssum);
    }

    #pragma unroll
    for (int off = 32; off > 0; off >>= 1) ssum += __shfl_down(ssum, off);
    if ((tid & 63) == 0) red[tid >> 6] = ssum;
    __syncthreads();
    if (tid == 0)
        partial[bx + GX * (by + GY * bz)] =
            red[0] + red[1] + red[2] + red[3];
}

__global__ __launch_bounds__(1024)
void ssim_reduce_kernel(const float* __restrict__ partial, float* __restrict__ out)
{
    __shared__ double red[16];
    double s = 0.0;
    for (int i = threadIdx.x; i < NBLOCKS; i += 1024) s += (double)partial[i];
    #pragma unroll
    for (int off = 32; off > 0; off >>= 1) s += __shfl_down(s, off);
    if ((threadIdx.x & 63) == 0) red[threadIdx.x >> 6] = s;
    __syncthreads();
    if (threadIdx.x == 0) {
        double t = 0.0;
        #pragma unroll
        for (int w = 0; w < 16; ++w) t += red[w];
        out[0] = (float)(t / NPIX);
    }
}

extern "C" void kernel_launch(void* const* d_in, const int* in_sizes, int n_in,
                              void* d_out, int out_size, void* d_ws, size_t ws_size,
                              hipStream_t stream)
{
    GaussW gw;
    double g[11], sum = 0.0;
    for (int i = 0; i < 11; ++i) {
        double x = (double)(i - 5);
        g[i] = exp(-(x * x) / 4.5);
        sum += g[i];
    }
    for (int i = 0; i < 11; ++i) gw.w[i] = (float)(g[i] / sum);

    const float* img1 = (const float*)d_in[0];
    const float* img2 = (const float*)d_in[1];
    float* partial = (float*)d_ws;   // NBLOCKS floats; every slot written each launch
    float* out = (float*)d_out;

    dim3 grid(GX, GY, NPLANE);
    hipLaunchKernelGGL(ssim_tile_kernel, grid, dim3(256), 0, stream,
                       img1, img2, partial, gw);
    hipLaunchKernelGGL(ssim_reduce_kernel, dim3(1), dim3(1024), 0, stream,
                       partial, out);
}